// Round 4
// baseline (376.010 us; speedup 1.0000x reference)
//
#include <hip/hip_runtime.h>
#include <hip/hip_bf16.h>
#include <stdint.h>

typedef __bf16 bf16x8 __attribute__((ext_vector_type(8)));
typedef float  f32x4  __attribute__((ext_vector_type(4)));
typedef __hip_bfloat16 bf16_t;

#define D_MODEL 1024
#define NH 16
#define DH 64
#define BB 2
#define SS 2048
#define MTOT (BB*SS)   /* 4096 */

#define GBM 128
#define GBN 128
#define GBK 64

// ---------------------------------------------------------------------------
// fp32 -> bf16 convert for q,k,v (one launch, 3 tensors)
// ---------------------------------------------------------------------------
__global__ void cvt_qkv_kernel(const float* __restrict__ q, const float* __restrict__ k,
                               const float* __restrict__ v, bf16_t* __restrict__ dst) {
  const int n1v = MTOT * D_MODEL / 4;  // float4 count per tensor
  int tid = blockIdx.x * blockDim.x + threadIdx.x;
  int stride = gridDim.x * blockDim.x;
  for (int i = tid; i < 3 * n1v; i += stride) {
    int which = i / n1v;
    int j = i - which * n1v;
    const float4* src = (const float4*)(which == 0 ? q : (which == 1 ? k : v));
    float4 f = src[j];
    union { bf16_t h[4]; short4 s4; } u;
    u.h[0] = __float2bfloat16(f.x);
    u.h[1] = __float2bfloat16(f.y);
    u.h[2] = __float2bfloat16(f.z);
    u.h[3] = __float2bfloat16(f.w);
    ((short4*)dst)[(size_t)which * n1v + j] = u.s4;
  }
}

// ---------------------------------------------------------------------------
// W [K][N] fp32  ->  Wt [N][K] bf16   (z = 0..3 selects Wq,Wk,Wv,Wo)
// ---------------------------------------------------------------------------
__global__ void transpose_w_kernel(const float* __restrict__ W0, const float* __restrict__ W1,
                                   const float* __restrict__ W2, const float* __restrict__ W3,
                                   bf16_t* __restrict__ WtAll) {
  __shared__ float tile[32][33];
  const int z = blockIdx.z;
  const float* W = (z == 0) ? W0 : (z == 1) ? W1 : (z == 2) ? W2 : W3;
  bf16_t* Wt = WtAll + (size_t)z * D_MODEL * D_MODEL;
  const int tx = threadIdx.x, ty = threadIdx.y;
  const int bx = blockIdx.x, by = blockIdx.y;
#pragma unroll
  for (int i = 0; i < 4; ++i)
    tile[ty + i * 8][tx] = W[(size_t)(by * 32 + ty + i * 8) * D_MODEL + bx * 32 + tx];
  __syncthreads();
#pragma unroll
  for (int i = 0; i < 4; ++i)
    Wt[(size_t)(bx * 32 + ty + i * 8) * D_MODEL + by * 32 + tx] =
        __float2bfloat16(tile[tx][ty + i * 8]);
}

// ---------------------------------------------------------------------------
// GEMM mainloop: C[128x128] tile, A [M][K] bf16 row-major, Bt [N][K] bf16.
// 256 threads = 4 waves (2x2), each wave 64x64 = 4x4 frags of 16x16.
// global_load_lds width-16 staging, single-buffered (m97 structure).
// ---------------------------------------------------------------------------
__device__ __forceinline__ void g2lds16(const bf16_t* g, bf16_t* l) {
  __builtin_amdgcn_global_load_lds((__attribute__((address_space(1))) void*)(g),
                                   (__attribute__((address_space(3))) void*)(l), 16, 0, 0);
}

__device__ __forceinline__ void gemm_tile_mainloop(const bf16_t* __restrict__ A,
                                                   const bf16_t* __restrict__ Bt,
                                                   bf16_t* As, bf16_t* Bs,
                                                   int m0, int n0, f32x4 acc[4][4]) {
  const int tid = threadIdx.x;
  const int wv = tid >> 6, ln = tid & 63;
  const int wr = wv >> 1, wc = wv & 1;
  const int lr = ln & 15, lg = ln >> 4;

#pragma unroll
  for (int mi = 0; mi < 4; ++mi)
#pragma unroll
    for (int ni = 0; ni < 4; ++ni)
      acc[mi][ni] = (f32x4){0.f, 0.f, 0.f, 0.f};

  for (int kt = 0; kt < D_MODEL / GBK; ++kt) {
    // stage A and B tiles: each wave issues 4+4 1KB direct-to-LDS loads
#pragma unroll
    for (int c = 0; c < 4; ++c) {
      int chunk = wv * 4 + c;
      int row = chunk * 8 + (ln >> 3);
      int col = (ln & 7) * 8;
      g2lds16(A  + (size_t)(m0 + row) * D_MODEL + kt * GBK + col, As + chunk * 8 * GBK);
      g2lds16(Bt + (size_t)(n0 + row) * D_MODEL + kt * GBK + col, Bs + chunk * 8 * GBK);
    }
    __syncthreads();
#pragma unroll
    for (int ks = 0; ks < 2; ++ks) {
      bf16x8 af[4], bfr[4];
#pragma unroll
      for (int mi = 0; mi < 4; ++mi)
        af[mi] = *(const bf16x8*)(As + (size_t)(wr * 64 + mi * 16 + lr) * GBK + ks * 32 + lg * 8);
#pragma unroll
      for (int ni = 0; ni < 4; ++ni)
        bfr[ni] = *(const bf16x8*)(Bs + (size_t)(wc * 64 + ni * 16 + lr) * GBK + ks * 32 + lg * 8);
#pragma unroll
      for (int mi = 0; mi < 4; ++mi)
#pragma unroll
        for (int ni = 0; ni < 4; ++ni)
          acc[mi][ni] = __builtin_amdgcn_mfma_f32_16x16x32_bf16(af[mi], bfr[ni], acc[mi][ni], 0, 0, 0);
    }
    __syncthreads();
  }
}

// ---------------------------------------------------------------------------
// Projection GEMM: z=0 -> Q (bf16 [M][N]), z=1 -> K (bf16 [M][N]),
// z=2 -> V written transposed as Vt[(b*1024 + n)][s]  (bf16)
// ---------------------------------------------------------------------------
__global__ __launch_bounds__(256)
void proj_gemm_kernel(const bf16_t* __restrict__ Aq, const bf16_t* __restrict__ Ak,
                      const bf16_t* __restrict__ Av, const bf16_t* __restrict__ WtAll,
                      const float* __restrict__ bq, const float* __restrict__ bk,
                      const float* __restrict__ bv,
                      bf16_t* __restrict__ Qg, bf16_t* __restrict__ Kg,
                      bf16_t* __restrict__ Vt) {
  __shared__ bf16_t As[GBM * GBK];
  __shared__ bf16_t Bs[GBN * GBK];
  const int z = blockIdx.z;
  const bf16_t* A = (z == 0) ? Aq : (z == 1) ? Ak : Av;
  const bf16_t* Bt = WtAll + (size_t)z * D_MODEL * D_MODEL;
  const float* bias = (z == 0) ? bq : (z == 1) ? bk : bv;
  const int m0 = blockIdx.y * GBM, n0 = blockIdx.x * GBN;

  f32x4 acc[4][4];
  gemm_tile_mainloop(A, Bt, As, Bs, m0, n0, acc);

  const int tid = threadIdx.x;
  const int wv = tid >> 6, ln = tid & 63;
  const int wr = wv >> 1, wc = wv & 1;
  const int lr = ln & 15, lg = ln >> 4;

#pragma unroll
  for (int mi = 0; mi < 4; ++mi) {
#pragma unroll
    for (int ni = 0; ni < 4; ++ni) {
      int ncol = n0 + wc * 64 + ni * 16 + lr;
      float bsv = bias[ncol];
#pragma unroll
      for (int j = 0; j < 4; ++j) {
        int mrow = m0 + wr * 64 + mi * 16 + lg * 4 + j;
        bf16_t hv = __float2bfloat16(acc[mi][ni][j] + bsv);
        if (z == 0) {
          Qg[(size_t)mrow * D_MODEL + ncol] = hv;
        } else if (z == 1) {
          Kg[(size_t)mrow * D_MODEL + ncol] = hv;
        } else {
          int b = mrow >> 11, s = mrow & (SS - 1);
          Vt[(size_t)((b << 10) | ncol) * SS + s] = hv;
        }
      }
    }
  }
}

// ---------------------------------------------------------------------------
// Output GEMM: ctx[M][K] bf16 @ Wo^T [N][K] bf16 + bo -> fp32 out [M][N]
// ---------------------------------------------------------------------------
__global__ __launch_bounds__(256)
void out_gemm_kernel(const bf16_t* __restrict__ Ctx, const bf16_t* __restrict__ Wto,
                     const float* __restrict__ bo, float* __restrict__ out) {
  __shared__ bf16_t As[GBM * GBK];
  __shared__ bf16_t Bs[GBN * GBK];
  const int m0 = blockIdx.y * GBM, n0 = blockIdx.x * GBN;

  f32x4 acc[4][4];
  gemm_tile_mainloop(Ctx, Wto, As, Bs, m0, n0, acc);

  const int tid = threadIdx.x;
  const int wv = tid >> 6, ln = tid & 63;
  const int wr = wv >> 1, wc = wv & 1;
  const int lr = ln & 15, lg = ln >> 4;

#pragma unroll
  for (int mi = 0; mi < 4; ++mi) {
#pragma unroll
    for (int ni = 0; ni < 4; ++ni) {
      int ncol = n0 + wc * 64 + ni * 16 + lr;
      float bsv = bo[ncol];
#pragma unroll
      for (int j = 0; j < 4; ++j) {
        int mrow = m0 + wr * 64 + mi * 16 + lg * 4 + j;
        out[(size_t)mrow * D_MODEL + ncol] = acc[mi][ni][j] + bsv;
      }
    }
  }
}

// ---------------------------------------------------------------------------
// Flash attention, causal. Block = 128 threads (2 waves), each wave 32 q-rows.
// KV tiles of 64. K,V fragments loaded straight from global (L2-resident).
// P transposed C-layout -> A-layout via per-wave padded LDS (no barriers).
// ---------------------------------------------------------------------------
__global__ __launch_bounds__(128)
void attn_kernel(const bf16_t* __restrict__ Qg, const bf16_t* __restrict__ Kg,
                 const bf16_t* __restrict__ Vt, bf16_t* __restrict__ Ctx) {
  __shared__ __align__(16) bf16_t P_lds[2][32][72];  // +8 pad: 2-way-free reads
  const int qt = blockIdx.x, bh = blockIdx.y;
  const int b = bh >> 4, h = bh & 15;
  const int wv = threadIdx.x >> 6, ln = threadIdx.x & 63;
  const int lr = ln & 15, lg = ln >> 4;
  const int q0 = qt * 64 + wv * 32;

  const size_t qkbase = (size_t)b * SS * D_MODEL + (size_t)h * DH;

  // Q fragments, scale 1/8 folded in (exact in bf16: exponent-only)
  bf16x8 qf[2][2];
#pragma unroll
  for (int mi = 0; mi < 2; ++mi)
#pragma unroll
    for (int ks = 0; ks < 2; ++ks) {
      bf16x8 raw = *(const bf16x8*)(Qg + qkbase + (size_t)(q0 + mi * 16 + lr) * D_MODEL + ks * 32 + lg * 8);
#pragma unroll
      for (int j = 0; j < 8; ++j) raw[j] = (__bf16)((float)raw[j] * 0.125f);
      qf[mi][ks] = raw;
    }

  f32x4 acc_o[2][4];
  float m_run[2][4], l_run[2][4];
#pragma unroll
  for (int mi = 0; mi < 2; ++mi) {
#pragma unroll
    for (int db = 0; db < 4; ++db) acc_o[mi][db] = (f32x4){0.f, 0.f, 0.f, 0.f};
#pragma unroll
    for (int j = 0; j < 4; ++j) { m_run[mi][j] = -1e30f; l_run[mi][j] = 0.f; }
  }

  const int ntiles = qt + 1;
  for (int t = 0; t < ntiles; ++t) {
    const int kv0 = t * 64;
    f32x4 sc[2][4];
#pragma unroll
    for (int mi = 0; mi < 2; ++mi)
#pragma unroll
      for (int kb = 0; kb < 4; ++kb) sc[mi][kb] = (f32x4){0.f, 0.f, 0.f, 0.f};

    // S = Q K^T (scaled)
#pragma unroll
    for (int ks = 0; ks < 2; ++ks) {
#pragma unroll
      for (int kb = 0; kb < 4; ++kb) {
        bf16x8 kf = *(const bf16x8*)(Kg + qkbase + (size_t)(kv0 + kb * 16 + lr) * D_MODEL + ks * 32 + lg * 8);
        sc[0][kb] = __builtin_amdgcn_mfma_f32_16x16x32_bf16(qf[0][ks], kf, sc[0][kb], 0, 0, 0);
        sc[1][kb] = __builtin_amdgcn_mfma_f32_16x16x32_bf16(qf[1][ks], kf, sc[1][kb], 0, 0, 0);
      }
    }

    // causal mask (only diagonal-crossing tiles; wave-uniform test)
    if (kv0 + 63 > q0) {
#pragma unroll
      for (int mi = 0; mi < 2; ++mi)
#pragma unroll
        for (int kb = 0; kb < 4; ++kb)
#pragma unroll
          for (int j = 0; j < 4; ++j) {
            int kc = kv0 + kb * 16 + lr;
            int qr = q0 + mi * 16 + lg * 4 + j;
            if (kc > qr) sc[mi][kb][j] = -1e30f;
          }
    }

    // online softmax; rows of a 16x16 frag live in the 16-lane group lg
#pragma unroll
    for (int mi = 0; mi < 2; ++mi) {
#pragma unroll
      for (int j = 0; j < 4; ++j) {
        float vmax = fmaxf(fmaxf(sc[mi][0][j], sc[mi][1][j]), fmaxf(sc[mi][2][j], sc[mi][3][j]));
#pragma unroll
        for (int off = 1; off < 16; off <<= 1) vmax = fmaxf(vmax, __shfl_xor(vmax, off, 64));
        float mo = m_run[mi][j];
        float mn = fmaxf(mo, vmax);
        float scl = __expf(mo - mn);
        m_run[mi][j] = mn;
        float rs = 0.f;
#pragma unroll
        for (int kb = 0; kb < 4; ++kb) {
          float p = __expf(sc[mi][kb][j] - mn);
          rs += p;
          P_lds[wv][mi * 16 + lg * 4 + j][kb * 16 + lr] = __float2bfloat16(p);
        }
#pragma unroll
        for (int off = 1; off < 16; off <<= 1) rs += __shfl_xor(rs, off, 64);
        l_run[mi][j] = l_run[mi][j] * scl + rs;
#pragma unroll
        for (int db = 0; db < 4; ++db) acc_o[mi][db][j] *= scl;
      }
    }

    // wave-internal LDS visibility (per-wave region, no barrier needed).
    // sched_barrier(0) per guide rule #18: prevent MFMA hoisting past the wait.
    asm volatile("s_waitcnt lgkmcnt(0)" ::: "memory");
    __builtin_amdgcn_sched_barrier(0);

    // O += P V
#pragma unroll
    for (int ks = 0; ks < 2; ++ks) {
      bf16x8 pa0 = *(const bf16x8*)(&P_lds[wv][lr][ks * 32 + lg * 8]);
      bf16x8 pa1 = *(const bf16x8*)(&P_lds[wv][16 + lr][ks * 32 + lg * 8]);
#pragma unroll
      for (int db = 0; db < 4; ++db) {
        bf16x8 vf = *(const bf16x8*)(Vt + (size_t)(bh * 64 + db * 16 + lr) * SS + kv0 + ks * 32 + lg * 8);
        acc_o[0][db] = __builtin_amdgcn_mfma_f32_16x16x32_bf16(pa0, vf, acc_o[0][db], 0, 0, 0);
        acc_o[1][db] = __builtin_amdgcn_mfma_f32_16x16x32_bf16(pa1, vf, acc_o[1][db], 0, 0, 0);
      }
    }
  }

  // epilogue: ctx = O / l, bf16 row-major [B*S][D_MODEL]
#pragma unroll
  for (int mi = 0; mi < 2; ++mi)
#pragma unroll
    for (int db = 0; db < 4; ++db)
#pragma unroll
      for (int j = 0; j < 4; ++j) {
        int qr = q0 + mi * 16 + lg * 4 + j;
        float val = acc_o[mi][db][j] / l_run[mi][j];
        Ctx[(size_t)(b * SS + qr) * D_MODEL + h * DH + db * 16 + lr] = __float2bfloat16(val);
      }
}

// ---------------------------------------------------------------------------
extern "C" void kernel_launch(void* const* d_in, const int* in_sizes, int n_in,
                              void* d_out, int out_size, void* d_ws, size_t ws_size,
                              hipStream_t stream) {
  const float* q  = (const float*)d_in[0];
  const float* k  = (const float*)d_in[1];
  const float* v  = (const float*)d_in[2];
  // d_in[3] = additive causal mask — applied analytically in attn_kernel
  const float* bq = (const float*)d_in[5];
  const float* bk = (const float*)d_in[7];
  const float* bv = (const float*)d_in[9];
  const float* bo = (const float*)d_in[11];
  const float* Wq = (const float*)d_in[4];
  const float* Wk = (const float*)d_in[6];
  const float* Wv = (const float*)d_in[8];
  const float* Wo = (const float*)d_in[10];
  float* out = (float*)d_out;

  char* w = (char*)d_ws;
  bf16_t* Aqkv  = (bf16_t*)(w);                       // 3 x [4096][1024] bf16
  bf16_t* WtAll = (bf16_t*)(w + 25165824);            // 4 x [1024][1024] bf16
  bf16_t* Qg    = (bf16_t*)(w + 33554432);            // [4096][1024] bf16
  bf16_t* Kg    = (bf16_t*)(w + 41943040);            // [4096][1024] bf16
  bf16_t* Vt    = (bf16_t*)(w + 50331648);            // [2048][2048] bf16 (per-b, n-major)
  bf16_t* Ctx   = (bf16_t*)(w + 58720256);            // [4096][1024] bf16

  cvt_qkv_kernel<<<2048, 256, 0, stream>>>(q, k, v, Aqkv);
  transpose_w_kernel<<<dim3(32, 32, 4), dim3(32, 8), 0, stream>>>(Wq, Wk, Wv, Wo, WtAll);
  proj_gemm_kernel<<<dim3(8, 32, 3), 256, 0, stream>>>(
      Aqkv, Aqkv + (size_t)MTOT * D_MODEL, Aqkv + 2 * (size_t)MTOT * D_MODEL,
      WtAll, bq, bk, bv, Qg, Kg, Vt);
  attn_kernel<<<dim3(32, 32), 128, 0, stream>>>(Qg, Kg, Vt, Ctx);
  out_gemm_kernel<<<dim3(8, 32), 256, 0, stream>>>(
      Ctx, WtAll + 3 * (size_t)D_MODEL * D_MODEL, bo, out);
}

// Round 5
// 297.499 us; speedup vs baseline: 1.2639x; 1.2639x over previous
//
#include <hip/hip_runtime.h>
#include <hip/hip_bf16.h>
#include <stdint.h>

typedef __bf16 bf16x8 __attribute__((ext_vector_type(8)));
typedef float  f32x4  __attribute__((ext_vector_type(4)));
typedef __hip_bfloat16 bf16_t;

#define D_MODEL 1024
#define NH 16
#define DH 64
#define BB 2
#define SS 2048
#define MTOT (BB*SS)   /* 4096 */

#define GBM 128
#define GBN 128
#define GBK 64

// ---------------------------------------------------------------------------
// fp32 -> bf16 convert for q,k,v (one launch, 3 tensors)
// ---------------------------------------------------------------------------
__global__ void cvt_qkv_kernel(const float* __restrict__ q, const float* __restrict__ k,
                               const float* __restrict__ v, bf16_t* __restrict__ dst) {
  const int n1v = MTOT * D_MODEL / 4;  // float4 count per tensor
  int tid = blockIdx.x * blockDim.x + threadIdx.x;
  int stride = gridDim.x * blockDim.x;
  for (int i = tid; i < 3 * n1v; i += stride) {
    int which = i / n1v;
    int j = i - which * n1v;
    const float4* src = (const float4*)(which == 0 ? q : (which == 1 ? k : v));
    float4 f = src[j];
    union { bf16_t h[4]; short4 s4; } u;
    u.h[0] = __float2bfloat16(f.x);
    u.h[1] = __float2bfloat16(f.y);
    u.h[2] = __float2bfloat16(f.z);
    u.h[3] = __float2bfloat16(f.w);
    ((short4*)dst)[(size_t)which * n1v + j] = u.s4;
  }
}

// ---------------------------------------------------------------------------
// W [K][N] fp32  ->  Wt [N][K] bf16   (z = 0..3 selects Wq,Wk,Wv,Wo)
// ---------------------------------------------------------------------------
__global__ void transpose_w_kernel(const float* __restrict__ W0, const float* __restrict__ W1,
                                   const float* __restrict__ W2, const float* __restrict__ W3,
                                   bf16_t* __restrict__ WtAll) {
  __shared__ float tile[32][33];
  const int z = blockIdx.z;
  const float* W = (z == 0) ? W0 : (z == 1) ? W1 : (z == 2) ? W2 : W3;
  bf16_t* Wt = WtAll + (size_t)z * D_MODEL * D_MODEL;
  const int tx = threadIdx.x, ty = threadIdx.y;
  const int bx = blockIdx.x, by = blockIdx.y;
#pragma unroll
  for (int i = 0; i < 4; ++i)
    tile[ty + i * 8][tx] = W[(size_t)(by * 32 + ty + i * 8) * D_MODEL + bx * 32 + tx];
  __syncthreads();
#pragma unroll
  for (int i = 0; i < 4; ++i)
    Wt[(size_t)(bx * 32 + ty + i * 8) * D_MODEL + by * 32 + tx] =
        __float2bfloat16(tile[tx][ty + i * 8]);
}

// ---------------------------------------------------------------------------
// GEMM mainloop: C[128x128] tile, A [M][K] bf16 row-major, Bt [N][K] bf16.
// 256 threads = 4 waves (2x2), each wave 64x64 = 4x4 frags of 16x16.
// global_load_lds width-16 staging, single-buffered (m97 structure).
// ---------------------------------------------------------------------------
__device__ __forceinline__ void g2lds16(const bf16_t* g, bf16_t* l) {
  __builtin_amdgcn_global_load_lds((__attribute__((address_space(1))) void*)(g),
                                   (__attribute__((address_space(3))) void*)(l), 16, 0, 0);
}

__device__ __forceinline__ void gemm_tile_mainloop(const bf16_t* __restrict__ A,
                                                   const bf16_t* __restrict__ Bt,
                                                   bf16_t* As, bf16_t* Bs,
                                                   int m0, int n0, f32x4 acc[4][4]) {
  const int tid = threadIdx.x;
  const int wv = tid >> 6, ln = tid & 63;
  const int wr = wv >> 1, wc = wv & 1;
  const int lr = ln & 15, lg = ln >> 4;

#pragma unroll
  for (int mi = 0; mi < 4; ++mi)
#pragma unroll
    for (int ni = 0; ni < 4; ++ni)
      acc[mi][ni] = (f32x4){0.f, 0.f, 0.f, 0.f};

  for (int kt = 0; kt < D_MODEL / GBK; ++kt) {
    // stage A and B tiles: each wave issues 4+4 1KB direct-to-LDS loads
#pragma unroll
    for (int c = 0; c < 4; ++c) {
      int chunk = wv * 4 + c;
      int row = chunk * 8 + (ln >> 3);
      int col = (ln & 7) * 8;
      g2lds16(A  + (size_t)(m0 + row) * D_MODEL + kt * GBK + col, As + chunk * 8 * GBK);
      g2lds16(Bt + (size_t)(n0 + row) * D_MODEL + kt * GBK + col, Bs + chunk * 8 * GBK);
    }
    __syncthreads();
#pragma unroll
    for (int ks = 0; ks < 2; ++ks) {
      bf16x8 af[4], bfr[4];
#pragma unroll
      for (int mi = 0; mi < 4; ++mi)
        af[mi] = *(const bf16x8*)(As + (size_t)(wr * 64 + mi * 16 + lr) * GBK + ks * 32 + lg * 8);
#pragma unroll
      for (int ni = 0; ni < 4; ++ni)
        bfr[ni] = *(const bf16x8*)(Bs + (size_t)(wc * 64 + ni * 16 + lr) * GBK + ks * 32 + lg * 8);
#pragma unroll
      for (int mi = 0; mi < 4; ++mi)
#pragma unroll
        for (int ni = 0; ni < 4; ++ni)
          acc[mi][ni] = __builtin_amdgcn_mfma_f32_16x16x32_bf16(af[mi], bfr[ni], acc[mi][ni], 0, 0, 0);
    }
    __syncthreads();
  }
}

// ---------------------------------------------------------------------------
// Projection GEMM: z=0 -> Q (bf16 [M][N]), z=1 -> K (bf16 [M][N]),
// z=2 -> V written transposed as Vt[(b*1024 + n)][s]  (bf16)
// ---------------------------------------------------------------------------
__global__ __launch_bounds__(256)
void proj_gemm_kernel(const bf16_t* __restrict__ Aq, const bf16_t* __restrict__ Ak,
                      const bf16_t* __restrict__ Av, const bf16_t* __restrict__ WtAll,
                      const float* __restrict__ bq, const float* __restrict__ bk,
                      const float* __restrict__ bv,
                      bf16_t* __restrict__ Qg, bf16_t* __restrict__ Kg,
                      bf16_t* __restrict__ Vt) {
  __shared__ bf16_t As[GBM * GBK];
  __shared__ bf16_t Bs[GBN * GBK];
  const int z = blockIdx.z;
  const bf16_t* A = (z == 0) ? Aq : (z == 1) ? Ak : Av;
  const bf16_t* Bt = WtAll + (size_t)z * D_MODEL * D_MODEL;
  const float* bias = (z == 0) ? bq : (z == 1) ? bk : bv;
  const int m0 = blockIdx.y * GBM, n0 = blockIdx.x * GBN;

  f32x4 acc[4][4];
  gemm_tile_mainloop(A, Bt, As, Bs, m0, n0, acc);

  const int tid = threadIdx.x;
  const int wv = tid >> 6, ln = tid & 63;
  const int wr = wv >> 1, wc = wv & 1;
  const int lr = ln & 15, lg = ln >> 4;

#pragma unroll
  for (int mi = 0; mi < 4; ++mi) {
#pragma unroll
    for (int ni = 0; ni < 4; ++ni) {
      int ncol = n0 + wc * 64 + ni * 16 + lr;
      float bsv = bias[ncol];
#pragma unroll
      for (int j = 0; j < 4; ++j) {
        int mrow = m0 + wr * 64 + mi * 16 + lg * 4 + j;
        bf16_t hv = __float2bfloat16(acc[mi][ni][j] + bsv);
        if (z == 0) {
          Qg[(size_t)mrow * D_MODEL + ncol] = hv;
        } else if (z == 1) {
          Kg[(size_t)mrow * D_MODEL + ncol] = hv;
        } else {
          int b = mrow >> 11, s = mrow & (SS - 1);
          Vt[(size_t)((b << 10) | ncol) * SS + s] = hv;
        }
      }
    }
  }
}

// ---------------------------------------------------------------------------
// Output GEMM: ctx[M][K] bf16 @ Wo^T [N][K] bf16 + bo -> fp32 out [M][N]
// ---------------------------------------------------------------------------
__global__ __launch_bounds__(256)
void out_gemm_kernel(const bf16_t* __restrict__ Ctx, const bf16_t* __restrict__ Wto,
                     const float* __restrict__ bo, float* __restrict__ out) {
  __shared__ bf16_t As[GBM * GBK];
  __shared__ bf16_t Bs[GBN * GBK];
  const int m0 = blockIdx.y * GBM, n0 = blockIdx.x * GBN;

  f32x4 acc[4][4];
  gemm_tile_mainloop(Ctx, Wto, As, Bs, m0, n0, acc);

  const int tid = threadIdx.x;
  const int wv = tid >> 6, ln = tid & 63;
  const int wr = wv >> 1, wc = wv & 1;
  const int lr = ln & 15, lg = ln >> 4;

#pragma unroll
  for (int mi = 0; mi < 4; ++mi) {
#pragma unroll
    for (int ni = 0; ni < 4; ++ni) {
      int ncol = n0 + wc * 64 + ni * 16 + lr;
      float bsv = bo[ncol];
#pragma unroll
      for (int j = 0; j < 4; ++j) {
        int mrow = m0 + wr * 64 + mi * 16 + lg * 4 + j;
        out[(size_t)mrow * D_MODEL + ncol] = acc[mi][ni][j] + bsv;
      }
    }
  }
}

// ---------------------------------------------------------------------------
// Flash attention, causal. Block = 128 threads (2 waves), each wave 32 q-rows.
// Grid: x = bh (fast axis, balances qt across CUs), y = qt reversed
// (longest blocks dispatch first).
// Register-prefetch: K(t+1) and V(t) loads issued before softmax(t) so
// VMEM latency hides under the exp/shuffle chain.
// Row-sum of P computed by an extra MFMA with an all-ones B fragment
// (replaces the 4-step shuffle sum-reduce).
// ---------------------------------------------------------------------------
__global__ __launch_bounds__(128)
void attn_kernel(const bf16_t* __restrict__ Qg, const bf16_t* __restrict__ Kg,
                 const bf16_t* __restrict__ Vt, bf16_t* __restrict__ Ctx) {
  __shared__ __align__(16) bf16_t P_lds[2][32][72];  // +8 pad: 2-way-free reads
  const int bh = blockIdx.x;
  const int qt = (int)gridDim.y - 1 - (int)blockIdx.y;  // longest first
  const int b = bh >> 4, h = bh & 15;
  const int wv = threadIdx.x >> 6, ln = threadIdx.x & 63;
  const int lr = ln & 15, lg = ln >> 4;
  const int q0 = qt * 64 + wv * 32;

  const size_t qkbase = (size_t)b * SS * D_MODEL + (size_t)h * DH;
  const bf16_t* Kbase = Kg + qkbase;
  const bf16_t* Vbase = Vt + (size_t)(bh * 64) * SS;

  // Q fragments, scale 1/8 folded in (exact in bf16: exponent-only)
  bf16x8 qf[2][2];
#pragma unroll
  for (int mi = 0; mi < 2; ++mi)
#pragma unroll
    for (int ks = 0; ks < 2; ++ks) {
      bf16x8 raw = *(const bf16x8*)(Qg + qkbase + (size_t)(q0 + mi * 16 + lr) * D_MODEL + ks * 32 + lg * 8);
#pragma unroll
      for (int j = 0; j < 8; ++j) raw[j] = (__bf16)((float)raw[j] * 0.125f);
      qf[mi][ks] = raw;
    }

  bf16x8 onesf;
#pragma unroll
  for (int j = 0; j < 8; ++j) onesf[j] = (__bf16)1.0f;

  f32x4 acc_o[2][4];
  f32x4 acc_l[2];
  float m_run[2][4];
#pragma unroll
  for (int mi = 0; mi < 2; ++mi) {
#pragma unroll
    for (int db = 0; db < 4; ++db) acc_o[mi][db] = (f32x4){0.f, 0.f, 0.f, 0.f};
    acc_l[mi] = (f32x4){0.f, 0.f, 0.f, 0.f};
#pragma unroll
    for (int j = 0; j < 4; ++j) m_run[mi][j] = -1e30f;
  }

  // prologue: K fragments for tile 0
  bf16x8 kf_cur[2][4];
#pragma unroll
  for (int ks = 0; ks < 2; ++ks)
#pragma unroll
    for (int kb = 0; kb < 4; ++kb)
      kf_cur[ks][kb] = *(const bf16x8*)(Kbase + (size_t)(kb * 16 + lr) * D_MODEL + ks * 32 + lg * 8);

  const int ntiles = qt + 1;
  for (int t = 0; t < ntiles; ++t) {
    const int kv0 = t * 64;
    f32x4 sc[2][4];
#pragma unroll
    for (int mi = 0; mi < 2; ++mi)
#pragma unroll
      for (int kb = 0; kb < 4; ++kb) sc[mi][kb] = (f32x4){0.f, 0.f, 0.f, 0.f};

    // S = Q K^T (scaled)
    __builtin_amdgcn_s_setprio(1);
#pragma unroll
    for (int ks = 0; ks < 2; ++ks) {
#pragma unroll
      for (int kb = 0; kb < 4; ++kb) {
        sc[0][kb] = __builtin_amdgcn_mfma_f32_16x16x32_bf16(qf[0][ks], kf_cur[ks][kb], sc[0][kb], 0, 0, 0);
        sc[1][kb] = __builtin_amdgcn_mfma_f32_16x16x32_bf16(qf[1][ks], kf_cur[ks][kb], sc[1][kb], 0, 0, 0);
      }
    }
    __builtin_amdgcn_s_setprio(0);

    // prefetch K(t+1): consumed ~softmax+PV later, fully hidden
    bf16x8 kf_nxt[2][4];
    if (t + 1 < ntiles) {
#pragma unroll
      for (int ks = 0; ks < 2; ++ks)
#pragma unroll
        for (int kb = 0; kb < 4; ++kb)
          kf_nxt[ks][kb] = *(const bf16x8*)(Kbase + (size_t)(kv0 + 64 + kb * 16 + lr) * D_MODEL + ks * 32 + lg * 8);
    }
    // prefetch V(t): consumed after softmax, hidden under the exp chain
    bf16x8 vf[2][4];
#pragma unroll
    for (int ks = 0; ks < 2; ++ks)
#pragma unroll
      for (int db = 0; db < 4; ++db)
        vf[ks][db] = *(const bf16x8*)(Vbase + (size_t)(db * 16 + lr) * SS + kv0 + ks * 32 + lg * 8);

    // causal mask (only diagonal-crossing tiles; wave-uniform test)
    if (kv0 + 63 > q0) {
#pragma unroll
      for (int mi = 0; mi < 2; ++mi)
#pragma unroll
        for (int kb = 0; kb < 4; ++kb)
#pragma unroll
          for (int j = 0; j < 4; ++j) {
            int kc = kv0 + kb * 16 + lr;
            int qr = q0 + mi * 16 + lg * 4 + j;
            if (kc > qr) sc[mi][kb][j] = -1e30f;
          }
    }

    // online softmax: row max via 4-step shuffle; row sum via MFMA later
#pragma unroll
    for (int mi = 0; mi < 2; ++mi) {
#pragma unroll
      for (int j = 0; j < 4; ++j) {
        float vmax = fmaxf(fmaxf(sc[mi][0][j], sc[mi][1][j]), fmaxf(sc[mi][2][j], sc[mi][3][j]));
#pragma unroll
        for (int off = 1; off < 16; off <<= 1) vmax = fmaxf(vmax, __shfl_xor(vmax, off, 64));
        float mo = m_run[mi][j];
        float mn = fmaxf(mo, vmax);
        float scl = __expf(mo - mn);
        m_run[mi][j] = mn;
#pragma unroll
        for (int kb = 0; kb < 4; ++kb) {
          float p = __expf(sc[mi][kb][j] - mn);
          P_lds[wv][mi * 16 + lg * 4 + j][kb * 16 + lr] = __float2bfloat16(p);
        }
        acc_l[mi][j] *= scl;
#pragma unroll
        for (int db = 0; db < 4; ++db) acc_o[mi][db][j] *= scl;
      }
    }

    // wave-internal LDS visibility (per-wave region, no barrier needed).
    // sched_barrier(0) per guide rule #18: prevent MFMA hoisting past the wait.
    asm volatile("s_waitcnt lgkmcnt(0)" ::: "memory");
    __builtin_amdgcn_sched_barrier(0);

    // O += P V ; l += P * 1 (row-sum via MFMA, replicated across cols)
    __builtin_amdgcn_s_setprio(1);
#pragma unroll
    for (int ks = 0; ks < 2; ++ks) {
      bf16x8 pa0 = *(const bf16x8*)(&P_lds[wv][lr][ks * 32 + lg * 8]);
      bf16x8 pa1 = *(const bf16x8*)(&P_lds[wv][16 + lr][ks * 32 + lg * 8]);
      acc_l[0] = __builtin_amdgcn_mfma_f32_16x16x32_bf16(pa0, onesf, acc_l[0], 0, 0, 0);
      acc_l[1] = __builtin_amdgcn_mfma_f32_16x16x32_bf16(pa1, onesf, acc_l[1], 0, 0, 0);
#pragma unroll
      for (int db = 0; db < 4; ++db) {
        acc_o[0][db] = __builtin_amdgcn_mfma_f32_16x16x32_bf16(pa0, vf[ks][db], acc_o[0][db], 0, 0, 0);
        acc_o[1][db] = __builtin_amdgcn_mfma_f32_16x16x32_bf16(pa1, vf[ks][db], acc_o[1][db], 0, 0, 0);
      }
    }
    __builtin_amdgcn_s_setprio(0);

    if (t + 1 < ntiles) {
#pragma unroll
      for (int ks = 0; ks < 2; ++ks)
#pragma unroll
        for (int kb = 0; kb < 4; ++kb)
          kf_cur[ks][kb] = kf_nxt[ks][kb];
    }
  }

  // epilogue: ctx = O / l, bf16 row-major [B*S][D_MODEL]
#pragma unroll
  for (int mi = 0; mi < 2; ++mi)
#pragma unroll
    for (int db = 0; db < 4; ++db)
#pragma unroll
      for (int j = 0; j < 4; ++j) {
        int qr = q0 + mi * 16 + lg * 4 + j;
        float val = acc_o[mi][db][j] / acc_l[mi][j];
        Ctx[(size_t)(b * SS + qr) * D_MODEL + h * DH + db * 16 + lr] = __float2bfloat16(val);
      }
}

// ---------------------------------------------------------------------------
extern "C" void kernel_launch(void* const* d_in, const int* in_sizes, int n_in,
                              void* d_out, int out_size, void* d_ws, size_t ws_size,
                              hipStream_t stream) {
  const float* q  = (const float*)d_in[0];
  const float* k  = (const float*)d_in[1];
  const float* v  = (const float*)d_in[2];
  // d_in[3] = additive causal mask — applied analytically in attn_kernel
  const float* bq = (const float*)d_in[5];
  const float* bk = (const float*)d_in[7];
  const float* bv = (const float*)d_in[9];
  const float* bo = (const float*)d_in[11];
  const float* Wq = (const float*)d_in[4];
  const float* Wk = (const float*)d_in[6];
  const float* Wv = (const float*)d_in[8];
  const float* Wo = (const float*)d_in[10];
  float* out = (float*)d_out;

  char* w = (char*)d_ws;
  bf16_t* Aqkv  = (bf16_t*)(w);                       // 3 x [4096][1024] bf16
  bf16_t* WtAll = (bf16_t*)(w + 25165824);            // 4 x [1024][1024] bf16
  bf16_t* Qg    = (bf16_t*)(w + 33554432);            // [4096][1024] bf16
  bf16_t* Kg    = (bf16_t*)(w + 41943040);            // [4096][1024] bf16
  bf16_t* Vt    = (bf16_t*)(w + 50331648);            // [2048][2048] bf16 (per-b, n-major)
  bf16_t* Ctx   = (bf16_t*)(w + 58720256);            // [4096][1024] bf16

  cvt_qkv_kernel<<<2048, 256, 0, stream>>>(q, k, v, Aqkv);
  transpose_w_kernel<<<dim3(32, 32, 4), dim3(32, 8), 0, stream>>>(Wq, Wk, Wv, Wo, WtAll);
  proj_gemm_kernel<<<dim3(8, 32, 3), 256, 0, stream>>>(
      Aqkv, Aqkv + (size_t)MTOT * D_MODEL, Aqkv + 2 * (size_t)MTOT * D_MODEL,
      WtAll, bq, bk, bv, Qg, Kg, Vt);
  attn_kernel<<<dim3(32, 32), 128, 0, stream>>>(Qg, Kg, Vt, Ctx);
  out_gemm_kernel<<<dim3(8, 32), 256, 0, stream>>>(
      Ctx, WtAll + 3 * (size_t)D_MODEL * D_MODEL, bo, out);
}